// Round 8
// baseline (237.032 us; speedup 1.0000x reference)
//
#include <hip/hip_runtime.h>
#include <hip/hip_fp16.h>
#include <math.h>

#define LRELU_ALPHA 0.2f
#define NEG_INF -1000000000.0f
#define L2E 1.44269504088896340736f  // log2(e)

constexpr int B_ = 8, N_ = 2048, FIN = 128, FOUT = 64;

typedef _Float16 __attribute__((ext_vector_type(8))) f16x8;
typedef float __attribute__((ext_vector_type(4))) f32x4;

// async global->LDS, 16B per lane; lane l's data lands at ldsbase + l*16
__device__ __forceinline__ void gload16(const void* g, void* l) {
  __builtin_amdgcn_global_load_lds(
      (const __attribute__((address_space(1))) void*)g,
      (__attribute__((address_space(3))) void*)l, 16, 0, 0);
}

// ---------------------------------------------------------------------------
// Kernel 1 (unchanged, proven): Wh = h @ W^T (fp32), emitted as fp16
// transposed WhT[b][o][n]; also s1 = Wh@a1, s2 = Wh@a2 (fp32).
// ---------------------------------------------------------------------------
__global__ __launch_bounds__(256) void k_wh(
    const float* __restrict__ h, const float* __restrict__ W,
    const float* __restrict__ a, unsigned short* __restrict__ WhT,
    float* __restrict__ s1, float* __restrict__ s2) {
  __shared__ float Wt[128][65];  // [f][o]: read bank (f+o)%32 -> conflict-free
  __shared__ float hs[16][128];

  const int t = threadIdx.x;
  const int row0 = blockIdx.x * 16;

  for (int e = t; e < 64 * 128; e += 256) {
    int o = e >> 7, f = e & 127;
    Wt[f][o] = W[e];
  }
  {
    const float4* hg = (const float4*)(h + (size_t)row0 * FIN);
    for (int i4 = t; i4 < 16 * 32; i4 += 256) {
      int r = i4 >> 5, f4 = i4 & 31;
      *(float4*)&hs[r][f4 * 4] = hg[i4];
    }
  }
  __syncthreads();

  const int wave = t >> 6, lane = t & 63;  // lane = o
  float acc[4] = {0.f, 0.f, 0.f, 0.f};
#pragma unroll 4
  for (int f4 = 0; f4 < 32; ++f4) {
    float w0 = Wt[4 * f4 + 0][lane], w1 = Wt[4 * f4 + 1][lane];
    float w2 = Wt[4 * f4 + 2][lane], w3 = Wt[4 * f4 + 3][lane];
#pragma unroll
    for (int r = 0; r < 4; ++r) {
      float4 hv = *(const float4*)&hs[wave * 4 + r][f4 * 4];
      acc[r] += hv.x * w0 + hv.y * w1 + hv.z * w2 + hv.w * w3;
    }
  }

  const float a1v = a[lane], a2v = a[64 + lane];
  const int b = row0 / N_;
#pragma unroll
  for (int r = 0; r < 4; ++r) {
    const int row = row0 + wave * 4 + r;
    const int n = row - b * N_;
    const float v = acc[r];
    WhT[((size_t)b * 64 + lane) * N_ + n] = __half_as_ushort(__float2half(v));
    float p1 = v * a1v, p2 = v * a2v;
#pragma unroll
    for (int d = 32; d; d >>= 1) {
      p1 += __shfl_xor(p1, d, 64);
      p2 += __shfl_xor(p2, d, 64);
    }
    if (lane == 0) { s1[row] = p1; s2[row] = p2; }
  }
}

// ---------------------------------------------------------------------------
// Kernel 2 v7b: j-split across waves -> private barrier-free pipelines.
// (v7 with the macro token-pasting compile error fixed: register names are
// passed explicitly instead of P##0, since `0.x` lexes as one pp-number.)
// Block = 16 i-rows, grid (B, N/16) = 1024 blocks = 4 blocks/CU. Wave w owns
// j in [w*512, (w+1)*512): 16 chunks of 32 j. Per chunk (6 vm-ops, private):
//   adj A-fragment direct to regs (2x int4: lane(q,m) = adj[i0+m][c*32+q*8..])
//   WhT 64o x 32j fp16 via 4x gload16 into the wave's OWN 4 KB LDS buffer
// Double-buffered; wave self-syncs with vmcnt(6) (chunk c landed, c+1 in
// flight) -- NO barriers in the main loop, no inter-wave sharing.
// exp computed exactly once per (i,j) element (v6 duplicated it 4x -> its
// VALUBusy 37% at 78us; v3b 2x). Each wave does 4 o-group MFMAs + ones-MFMA
// rowsum into partial accumulators over its j-quarter.
// LDS: 2 bufs x 4 waves x 4 KB = 32 KB + s2s 8 KB = 40960 B -> exactly
// 4 blocks/CU. Epilogue: each wave writes partials into its OWN freed
// buffers (buf0: 16x64 acc, buf1: 16 rowsums -- no cross-wave write race),
// one __syncthreads, then 256-thread reduce over the 4 j-partials + (-2)-
// shifted softmax normalize (partials combine exactly: fixed shift).
// ---------------------------------------------------------------------------
__global__ __launch_bounds__(256, 4) void k_attn(
    const unsigned short* __restrict__ WhT,
    const float* __restrict__ s1g, const float* __restrict__ s2g,
    const int* __restrict__ adj, float* __restrict__ out) {
  __shared__ __align__(16) unsigned char sbuf[2][16 * 1024];
  __shared__ float s2s[N_];

  const int t = threadIdx.x;
  const int wave = t >> 6, lane = t & 63;
  const int m = lane & 15, q = lane >> 4;
  const int b = blockIdx.x;        // batch -> per-XCD L2 holds one WhT (2 MB)
  const int i0 = blockIdx.y * 16;
  const int jw = wave * 512;       // this wave's j-base

  // preload s2 row (8 KB), pre-scaled by log2(e)
  {
    const float4* s2R = (const float4*)(s2g + (size_t)b * N_);
    for (int i = t; i < N_ / 4; i += 256) {
      float4 v = s2R[i];
      v.x *= L2E; v.y *= L2E; v.z *= L2E; v.w *= L2E;
      ((float4*)s2s)[i] = v;
    }
  }

  // A-fragment row of lane (q,m) is i0+m for all q
  const float s1r = s1g[b * N_ + i0 + m];
  const float c1 = (s1r - 2.0f) * L2E;                // x-2 branch (base-2)
  const float c2 = (LRELU_ALPHA * s1r - 2.0f) * L2E;  // 0.2x-2 branch

  f16x8 ones;
#pragma unroll
  for (int j = 0; j < 8; ++j) ones[j] = (_Float16)1.0f;

  // per-lane global sources for this wave's j-quarter
  const int* adjR =
      adj + (size_t)b * N_ * N_ + (size_t)(i0 + m) * N_ + jw + q * 8;
  const unsigned short* whL =
      WhT + (size_t)b * 64 * N_ + (size_t)m * N_ + jw + q * 8;  // + g*16*N_

  unsigned char* d0 = sbuf[0] + wave * 4096;  // private LDS bufs (uniform base)
  unsigned char* d1 = sbuf[1] + wave * 4096;

#define STAGE(D, c)                                                       \
  {                                                                       \
    _Pragma("unroll") for (int g = 0; g < 4; ++g)                         \
        gload16(whL + (size_t)g * 16 * N_ + (c) * 32, (D) + g * 1024);    \
  }
#define ISSUE(R0, R1, c)                                 \
  {                                                      \
    const int4* ap = (const int4*)(adjR + (c) * 32);     \
    R0 = ap[0];                                          \
    R1 = ap[1];                                          \
  }
#define CONSUME(R0, R1, D, c)                                                \
  {                                                                          \
    const float* sp = &s2s[jw + (c) * 32 + q * 8];                           \
    float4 sv0 = *(const float4*)sp;                                         \
    float4 sv1 = *(const float4*)(sp + 4);                                   \
    float xs[8] = {sv0.x, sv0.y, sv0.z, sv0.w, sv1.x, sv1.y, sv1.z, sv1.w};  \
    int avs[8] = {R0.x, R0.y, R0.z, R0.w, R1.x, R1.y, R1.z, R1.w};           \
    f16x8 af;                                                                \
    _Pragma("unroll") for (int j = 0; j < 8; ++j) {                          \
      float x = xs[j];                                                       \
      float e = fmaxf(c1 + x, fmaf(LRELU_ALPHA, x, c2));                     \
      e = avs[j] ? e : NEG_INF;                                              \
      af[j] = (_Float16)__builtin_amdgcn_exp2f(e);  /* masked -> exactly 0 */\
    }                                                                        \
    f16x8 bf0 = *(const f16x8*)((D) + 0 * 1024 + lane * 16);                 \
    f16x8 bf1 = *(const f16x8*)((D) + 1 * 1024 + lane * 16);                 \
    f16x8 bf2 = *(const f16x8*)((D) + 2 * 1024 + lane * 16);                 \
    f16x8 bf3 = *(const f16x8*)((D) + 3 * 1024 + lane * 16);                 \
    acc0 = __builtin_amdgcn_mfma_f32_16x16x32_f16(af, bf0, acc0, 0, 0, 0);   \
    acc1 = __builtin_amdgcn_mfma_f32_16x16x32_f16(af, bf1, acc1, 0, 0, 0);   \
    acc2 = __builtin_amdgcn_mfma_f32_16x16x32_f16(af, bf2, acc2, 0, 0, 0);   \
    acc3 = __builtin_amdgcn_mfma_f32_16x16x32_f16(af, bf3, acc3, 0, 0, 0);   \
    accS = __builtin_amdgcn_mfma_f32_16x16x32_f16(af, ones, accS, 0, 0, 0);  \
  }
#define FV(NN) asm volatile("s_waitcnt vmcnt(" #NN ")" ::: "memory");
#define FL() asm volatile("s_waitcnt lgkmcnt(0)" ::: "memory");

  int4 rA0, rA1, rB0, rB1;
  f32x4 acc0 = {0.f, 0.f, 0.f, 0.f}, acc1 = acc0, acc2 = acc0, acc3 = acc0,
        accS = acc0;

  __syncthreads();  // publish s2s BEFORE prefetch (keeps prologue in flight)

  ISSUE(rA0, rA1, 0) STAGE(d0, 0)
  ISSUE(rB0, rB1, 1) STAGE(d1, 1)

  for (int c = 0; c < 14; c += 2) {
    FV(6) CONSUME(rA0, rA1, d0, c)   // chunk c landed; c+1 stays in flight
    FL() ISSUE(rA0, rA1, c + 2) STAGE(d0, c + 2)
    FV(6) CONSUME(rB0, rB1, d1, c + 1)
    FL() ISSUE(rB0, rB1, c + 3) STAGE(d1, c + 3)
  }
  FV(6) CONSUME(rA0, rA1, d0, 14)
  FV(0) CONSUME(rB0, rB1, d1, 15)

  // epilogue: write partials into OWN freed buffers (no cross-wave race):
  // buf0 <- 16x64 acc partial, buf1 <- 16 rowsum partials.
  {
    float* redw = (float*)d0;
#pragma unroll
    for (int r = 0; r < 4; ++r) {
      redw[(q * 4 + r) * 64 + 0 * 16 + m] = acc0[r];
      redw[(q * 4 + r) * 64 + 1 * 16 + m] = acc1[r];
      redw[(q * 4 + r) * 64 + 2 * 16 + m] = acc2[r];
      redw[(q * 4 + r) * 64 + 3 * 16 + m] = acc3[r];
    }
    if (m == 0) {
      float* redSw = (float*)d1;
#pragma unroll
      for (int r = 0; r < 4; ++r) redSw[q * 4 + r] = accS[r];
    }
  }
  __syncthreads();

  // reduce the 4 j-partials and normalize (fixed -2 shift: exact combine)
  {
    const int row = t >> 4, c4 = t & 15;
    float4 v = {0.f, 0.f, 0.f, 0.f};
    float l = 0.f;
#pragma unroll
    for (int w2 = 0; w2 < 4; ++w2) {
      float4 pv = ((const float4*)(sbuf[0] + w2 * 4096))[row * 16 + c4];
      v.x += pv.x; v.y += pv.y; v.z += pv.z; v.w += pv.w;
      l += ((const float*)(sbuf[1] + w2 * 4096))[row];
    }
    const float inv = (l == 0.f) ? 1.f : 1.f / l;  // fully-masked row guard
    float4 o;
    o.x = v.x * inv; o.y = v.y * inv; o.z = v.z * inv; o.w = v.w * inv;
    ((float4*)(out + ((size_t)b * N_ + i0 + row) * FOUT))[c4] = o;
  }
#undef STAGE
#undef ISSUE
#undef CONSUME
#undef FV
#undef FL
}

extern "C" void kernel_launch(void* const* d_in, const int* in_sizes, int n_in,
                              void* d_out, int out_size, void* d_ws, size_t ws_size,
                              hipStream_t stream) {
  const float* h   = (const float*)d_in[0];
  const int*   adj = (const int*)d_in[1];
  const float* W   = (const float*)d_in[2];
  const float* a   = (const float*)d_in[3];
  float* out = (float*)d_out;

  // ws: WhT fp16 (2 MB) | s1 (64 KB) | s2 (64 KB)
  unsigned short* WhT = (unsigned short*)d_ws;
  float* s1 = (float*)(WhT + (size_t)B_ * 64 * N_);
  float* s2 = s1 + (size_t)B_ * N_;

  k_wh<<<dim3(B_ * N_ / 16), 256, 0, stream>>>(h, W, a, WhT, s1, s2);
  k_attn<<<dim3(B_, N_ / 16), 256, 0, stream>>>(WhT, s1, s2, adj, out);
}